// Round 5
// baseline (167.528 us; speedup 1.0000x reference)
//
#include <hip/hip_runtime.h>

#define NN   120000
#define NP   120064   // 1876 * 64, padded rows
#define EPSV 1e-5f
#define NSLICE 32

typedef __attribute__((ext_vector_type(8))) short          short8v;   // bf16 MFMA frag
typedef __attribute__((ext_vector_type(8))) unsigned short ushort8v;
typedef __attribute__((ext_vector_type(4))) float          f32x4;

typedef __attribute__((address_space(1))) const unsigned int gas_u32;
typedef __attribute__((address_space(3))) unsigned int       las_u32;

__device__ __forceinline__ float b2f(unsigned short u) {
    union { unsigned int i; float f; } x; x.i = ((unsigned int)u) << 16; return x.f;
}
__device__ __forceinline__ unsigned short f2b(float f) {
    union { float f; unsigned int i; } x; x.f = f;
    unsigned int i = x.i + 0x7FFFu + ((x.i >> 16) & 1u);
    return (unsigned short)(i >> 16);
}

// ---------------------------------------------------------------------------
// wprep: w2/w3/w4 (f32 [cout][kd]) -> bf16 MFMA-fragment-linear layout.
// frag addr: ((cb*KBLK + kb)*64 + lane)*8 + e  where col=cb*16+(lane&15),
// k = kb*32 + (lane>>4)*8 + e.
// ---------------------------------------------------------------------------
__global__ __launch_bounds__(256) void wprep_kernel(
    const float* __restrict__ w2, const float* __restrict__ w3,
    const float* __restrict__ w4, unsigned short* __restrict__ wb)
{
    int t = blockIdx.x * 256 + threadIdx.x;
    const float* src; int KD, ks; unsigned short* dst; int f;
    if (t < 16384)      { src = w2; KD = 128; ks = 2; dst = wb;         f = t; }
    else if (t < 49152) { src = w3; KD = 128; ks = 2; dst = wb + 16384; f = t - 16384; }
    else                { src = w4; KD = 256; ks = 3; dst = wb + 49152; f = t - 49152; }
    int e = f & 7, l = (f >> 3) & 63;
    int rest = f >> 9;
    int kb = rest & ((1 << ks) - 1);
    int cb = rest >> ks;
    int col = cb * 16 + (l & 15);
    int k = kb * 32 + (l >> 4) * 8 + e;
    dst[f] = f2b(src[col * KD + k]);
}

// ---------------------------------------------------------------------------
// K1: y1 = feat @ w1.T (K=5), raw bf16 output, sliced per-channel stats.
// ---------------------------------------------------------------------------
__global__ __launch_bounds__(256) void k1_kernel(
    const float* __restrict__ feat, const float* __restrict__ w1,
    unsigned short* __restrict__ y1, float* __restrict__ stat1)
{
    __shared__ float red[1024];
    const int tid = threadIdx.x;
    const int g = tid & 15;
    const int rsub = tid >> 4;
    const int rowbase = blockIdx.x * 128;

    float wr_[8][5];
#pragma unroll
    for (int j = 0; j < 8; ++j)
#pragma unroll
        for (int k = 0; k < 5; ++k)
            wr_[j][k] = w1[(g * 8 + j) * 5 + k];

    float ss[8] = {}, qq[8] = {};
#pragma unroll
    for (int p = 0; p < 8; ++p) {
        int row = rowbase + p * 16 + rsub;
        float f0 = 0.f, f1 = 0.f, f2 = 0.f, f3 = 0.f, f4 = 0.f;
        if (row < NN) {
            const float* fp = feat + (size_t)row * 5;
            f0 = fp[0]; f1 = fp[1]; f2 = fp[2]; f3 = fp[3]; f4 = fp[4];
        }
        ushort8v o;
#pragma unroll
        for (int j = 0; j < 8; ++j) {
            float y = f0*wr_[j][0] + f1*wr_[j][1] + f2*wr_[j][2] + f3*wr_[j][3] + f4*wr_[j][4];
            o[j] = f2b(y);
            ss[j] += y; qq[j] += y * y;
        }
        *(ushort8v*)(y1 + (size_t)row * 128 + g * 8) = o;
    }
#pragma unroll
    for (int j = 0; j < 8; ++j) {
        ss[j] += __shfl_xor(ss[j], 16); ss[j] += __shfl_xor(ss[j], 32);
        qq[j] += __shfl_xor(qq[j], 16); qq[j] += __shfl_xor(qq[j], 32);
    }
    const int w = tid >> 6, l = tid & 63;
    if ((l >> 4) == 0) {
#pragma unroll
        for (int j = 0; j < 8; ++j) {
            red[w * 128 + g * 8 + j]       = ss[j];
            red[512 + w * 128 + g * 8 + j] = qq[j];
        }
    }
    __syncthreads();
    if (tid < 128) {
        float s = red[tid] + red[128 + tid] + red[256 + tid] + red[384 + tid];
        float q = red[512 + tid] + red[640 + tid] + red[768 + tid] + red[896 + tid];
        float* dst = stat1 + (blockIdx.x & (NSLICE - 1)) * 256;
        atomicAdd(dst + tid,       s);
        atomicAdd(dst + 128 + tid, q);
    }
}

// ---------------------------------------------------------------------------
// GEMM v3: 64 rows x COUT per block, grid 1876. Raw X staged HBM->LDS via
// global_load_lds (pre-swizzled source -> XOR-swizzled LDS). BN+relu applied
// at fragment-load. B frags per-use from L2-hot fragment-linear weights.
// No persistent register arrays beyond the accumulator.
// ---------------------------------------------------------------------------
template<int KD, int COUT>
__global__ __launch_bounds__(256, (COUT == 256) ? 3 : 4) void gemm_bn_kernel(
    const unsigned short* __restrict__ X, const float* __restrict__ statsIn,
    const float* __restrict__ gIn, const float* __restrict__ bIn,
    const unsigned short* __restrict__ Wf, unsigned short* __restrict__ Y,
    float* __restrict__ statsOut)
{
    constexpr int KDB    = KD * 2;              // bytes per LDS row
    constexpr int NKK    = KD / 32;             // MFMA k-steps
    constexpr int NNI    = COUT / 32;           // col-groups per wave
    constexpr int KBLK   = KD / 32;
    constexpr int ROUNDS = (64 * KDB) / 4096;   // 4 (KD=128) or 8 (KD=256)
    constexpr int PITCH  = COUT * 2 + 16;       // writeback scratch pitch
    constexpr int UPT    = (COUT * 2 / 16) / 8; // 16B units per thread per row

    __shared__ char  As[32768];
    __shared__ float scl[KD], bia[KD];
    __shared__ float red[4 * COUT];

    const int tid = threadIdx.x;
    const int l = tid & 63, wv = tid >> 6;
    const int wr = wv >> 1, wc = wv & 1;
    const int lm = l & 15, lg = l >> 4;
    const int rowbase = blockIdx.x * 64;

    // ---- stage raw X tile (64 x KD bf16) into swizzled LDS via DMA ----
    // LDS[row][colb] must hold X[row][colb ^ swz(row)]; DMA writes linear,
    // so the per-lane GLOBAL address carries the swizzle.
#pragma unroll
    for (int rnd = 0; rnd < ROUNDS; ++rnd) {
        int s = rnd * 4096 + wv * 1024 + l * 16;     // linear LDS byte slot
        int row = s / KDB;
        int colb = s % KDB;
        int srcb = colb ^ ((row & 7) << 4);
        const unsigned short* g = X + (size_t)(rowbase + row) * KD + (srcb >> 1);
        __builtin_amdgcn_global_load_lds((gas_u32*)g,
            (las_u32*)(As + rnd * 4096 + wv * 1024), 16, 0, 0);
    }

    // ---- BN params from sliced stats ----
    if (tid < KD) {
        float s = 0.f, q = 0.f;
#pragma unroll 8
        for (int j = 0; j < NSLICE; ++j) {
            s += statsIn[j * 2 * KD + tid];
            q += statsIn[j * 2 * KD + KD + tid];
        }
        float mean = s * (1.0f / NN);
        float var  = q * (1.0f / NN) - mean * mean;
        float sc   = gIn[tid] * rsqrtf(var + EPSV);
        scl[tid] = sc;
        bia[tid] = bIn[tid] - mean * sc;
    }

    asm volatile("s_waitcnt vmcnt(0)" ::: "memory");
    __syncthreads();

    // ---- MFMA: A-frag from LDS (+BN+relu in regs), B-frag from global ----
    f32x4 acc[2][NNI] = {};
#pragma unroll
    for (int kk = 0; kk < NKK; ++kk) {
        int k0 = kk * 32 + lg * 8;
        f32x4 s0 = *(const f32x4*)(scl + k0);
        f32x4 s1 = *(const f32x4*)(scl + k0 + 4);
        f32x4 c0 = *(const f32x4*)(bia + k0);
        f32x4 c1 = *(const f32x4*)(bia + k0 + 4);
        short8v a[2];
#pragma unroll
        for (int mi = 0; mi < 2; ++mi) {
            int row = wr * 32 + mi * 16 + lm;
            ushort8v raw = *(const ushort8v*)(As + row * KDB + ((kk * 64 + lg * 16) ^ ((row & 7) << 4)));
            ushort8v o;
#pragma unroll
            for (int j = 0; j < 4; ++j)
                o[j] = f2b(fmaxf(b2f(raw[j]) * s0[j] + c0[j], 0.f));
#pragma unroll
            for (int j = 0; j < 4; ++j)
                o[4 + j] = f2b(fmaxf(b2f(raw[4 + j]) * s1[j] + c1[j], 0.f));
            a[mi] = (short8v)o;
        }
#pragma unroll
        for (int ni = 0; ni < NNI; ++ni) {
            int cb = wc * NNI + ni;
            short8v b = *(const short8v*)(Wf + ((size_t)(cb * KBLK + kk) * 64 + l) * 8);
            acc[0][ni] = __builtin_amdgcn_mfma_f32_16x16x32_bf16(a[0], b, acc[0][ni], 0, 0, 0);
            acc[1][ni] = __builtin_amdgcn_mfma_f32_16x16x32_bf16(a[1], b, acc[1][ni], 0, 0, 0);
        }
    }

    // ---- per-channel stats: reg -> shfl -> LDS -> one atomic/channel/block ----
#pragma unroll
    for (int ni = 0; ni < NNI; ++ni) {
        float s = 0.f, q = 0.f;
#pragma unroll
        for (int mi = 0; mi < 2; ++mi)
#pragma unroll
            for (int r = 0; r < 4; ++r) {
                int rowg = rowbase + wr * 32 + mi * 16 + lg * 4 + r;
                float v = (rowg < NN) ? acc[mi][ni][r] : 0.f;
                s += v; q += v * v;
            }
        s += __shfl_xor(s, 16); s += __shfl_xor(s, 32);
        q += __shfl_xor(q, 16); q += __shfl_xor(q, 32);
        if (lg == 0) {
            int ch = wc * (COUT / 2) + ni * 16 + lm;
            red[wr * COUT + ch]            = s;
            red[2 * COUT + wr * COUT + ch] = q;
        }
    }
    __syncthreads();
    {
        int slice = blockIdx.x & (NSLICE - 1);
        for (int ch = tid; ch < COUT; ch += 256) {
            atomicAdd(statsOut + (size_t)slice * 2 * COUT + ch,
                      red[ch] + red[COUT + ch]);
            atomicAdd(statsOut + (size_t)slice * 2 * COUT + COUT + ch,
                      red[2 * COUT + ch] + red[3 * COUT + ch]);
        }
    }

    // ---- writeback via As scratch, two 32-row passes, coalesced stores ----
#pragma unroll
    for (int p = 0; p < 2; ++p) {
        if (wr == p) {
#pragma unroll
            for (int mi = 0; mi < 2; ++mi)
#pragma unroll
                for (int ni = 0; ni < NNI; ++ni)
#pragma unroll
                    for (int r = 0; r < 4; ++r) {
                        int rloc = mi * 16 + lg * 4 + r;
                        int col = wc * (COUT / 2) + ni * 16 + lm;
                        *(unsigned short*)(As + rloc * PITCH + col * 2) = f2b(acc[mi][ni][r]);
                    }
        }
        __syncthreads();
        {
            int rloc = tid >> 3;
            int u0 = (tid & 7) * UPT;
            unsigned short* Yrow = Y + (size_t)(rowbase + p * 32 + rloc) * COUT + u0 * 8;
#pragma unroll
            for (int u = 0; u < UPT; ++u)
                *(ushort8v*)(Yrow + u * 8) =
                    *(const ushort8v*)(As + rloc * PITCH + (u0 + u) * 16);
        }
        if (p == 0) __syncthreads();
    }
}

// ---------------------------------------------------------------------------
// K5: x5 = relu( BN4(y4) + relu(BN2(y2)) ); logits = x5 @ w_out.T + b_out
// ---------------------------------------------------------------------------
__global__ __launch_bounds__(256) void k5_kernel(
    const unsigned short* __restrict__ y2, const unsigned short* __restrict__ y4,
    const float* __restrict__ stat2, const float* __restrict__ g2, const float* __restrict__ b2,
    const float* __restrict__ stat4, const float* __restrict__ g4, const float* __restrict__ b4,
    const float* __restrict__ w_out, const float* __restrict__ b_out,
    float* __restrict__ out)
{
    __shared__ float wT[128 * 8];
    __shared__ float sc2[128], bi2[128], sc4[128], bi4[128], bo[8];
    const int tid = threadIdx.x;

    if (tid < 128) {
        float s2 = 0.f, q2 = 0.f, s4 = 0.f, q4 = 0.f;
#pragma unroll 8
        for (int j = 0; j < NSLICE; ++j) {
            s2 += stat2[j * 256 + tid];       q2 += stat2[j * 256 + 128 + tid];
            s4 += stat4[j * 256 + tid];       q4 += stat4[j * 256 + 128 + tid];
        }
        float m2 = s2 * (1.0f / NN);
        float v2 = q2 * (1.0f / NN) - m2 * m2;
        float t2 = g2[tid] * rsqrtf(v2 + EPSV);
        sc2[tid] = t2; bi2[tid] = b2[tid] - m2 * t2;
        float m4 = s4 * (1.0f / NN);
        float v4 = q4 * (1.0f / NN) - m4 * m4;
        float t4 = g4[tid] * rsqrtf(v4 + EPSV);
        sc4[tid] = t4; bi4[tid] = b4[tid] - m4 * t4;
    }
    for (int i = tid; i < 1024; i += 256) wT[i] = w_out[(i & 7) * 128 + (i >> 3)];
    if (tid < 8) bo[tid] = b_out[tid];
    __syncthreads();

    const int l = tid & 63, wv = tid >> 6;
    const int sub = l & 7, rl = l >> 3;
    const int row = blockIdx.x * 32 + wv * 8 + rl;   // 3750*32 = 120000

    const ushort8v* p2 = (const ushort8v*)(y2 + (size_t)row * 128 + sub * 16);
    const ushort8v* p4 = (const ushort8v*)(y4 + (size_t)row * 128 + sub * 16);

    float p[8];
#pragma unroll
    for (int o = 0; o < 8; ++o) p[o] = 0.f;

#pragma unroll
    for (int jj = 0; jj < 2; ++jj) {
        ushort8v a2 = p2[jj];
        ushort8v a4 = p4[jj];
#pragma unroll
        for (int e = 0; e < 8; ++e) {
            int c = sub * 16 + jj * 8 + e;
            float i2 = fmaxf(b2f(a2[e]) * sc2[c] + bi2[c], 0.f);
            float x4 = b2f(a4[e]) * sc4[c] + bi4[c];
            float x5 = fmaxf(x4 + i2, 0.f);
            const f32x4* wp = (const f32x4*)(wT + c * 8);
            f32x4 wa = wp[0], wb = wp[1];
            p[0] += x5 * wa[0]; p[1] += x5 * wa[1]; p[2] += x5 * wa[2]; p[3] += x5 * wa[3];
            p[4] += x5 * wb[0]; p[5] += x5 * wb[1]; p[6] += x5 * wb[2]; p[7] += x5 * wb[3];
        }
    }
#pragma unroll
    for (int o = 0; o < 8; ++o) {
        p[o] += __shfl_xor(p[o], 1);
        p[o] += __shfl_xor(p[o], 2);
        p[o] += __shfl_xor(p[o], 4);
    }
    out[(size_t)row * 8 + sub] = p[sub] + bo[sub];
}

// ---------------------------------------------------------------------------
extern "C" void kernel_launch(void* const* d_in, const int* in_sizes, int n_in,
                              void* d_out, int out_size, void* d_ws, size_t ws_size,
                              hipStream_t stream)
{
    const float* feat  = (const float*)d_in[0];
    // d_in[1] coord, d_in[2] knn_idx, d_in[3] offset: dead code in reference
    const float* w1    = (const float*)d_in[4];
    const float* g1    = (const float*)d_in[5];
    const float* b1    = (const float*)d_in[6];
    const float* w2    = (const float*)d_in[7];
    const float* g2    = (const float*)d_in[8];
    const float* b2    = (const float*)d_in[9];
    const float* w3    = (const float*)d_in[10];
    const float* g3    = (const float*)d_in[11];
    const float* b3    = (const float*)d_in[12];
    const float* w4    = (const float*)d_in[13];
    const float* g4    = (const float*)d_in[14];
    const float* b4    = (const float*)d_in[15];
    const float* w_out = (const float*)d_in[16];
    const float* b_out = (const float*)d_in[17];

    char* ws = (char*)d_ws;
    const size_t sz128 = (size_t)NP * 128 * 2;   // bf16 N x 128
    const size_t sz256 = (size_t)NP * 256 * 2;   // bf16 N x 256
    unsigned short* y1 = (unsigned short*)(ws);
    unsigned short* y2 = (unsigned short*)(ws + sz128);
    unsigned short* y3 = (unsigned short*)(ws + 2 * sz128);
    unsigned short* y4 = (unsigned short*)(ws + 2 * sz128 + sz256);
    float* stats       = (float*)(ws + 3 * sz128 + sz256);
    // sliced stats: [32][2][C]
    float* stat1 = stats;            // 32*2*128 = 8192
    float* stat2 = stats + 8192;     // 8192
    float* stat3 = stats + 16384;    // 32*2*256 = 16384
    float* stat4 = stats + 32768;    // 8192
    unsigned short* wb = (unsigned short*)(stats + 40960);  // 81920 bf16 frag weights

    hipMemsetAsync(stats, 0, 40960 * sizeof(float), stream);

    wprep_kernel<<<dim3(320), 256, 0, stream>>>(w2, w3, w4, wb);
    k1_kernel<<<dim3(938), 256, 0, stream>>>(feat, w1, y1, stat1);
    gemm_bn_kernel<128, 128><<<dim3(1876), 256, 0, stream>>>(y1, stat1, g1, b1, wb,         y2, stat2);
    gemm_bn_kernel<128, 256><<<dim3(1876), 256, 0, stream>>>(y2, stat2, g2, b2, wb + 16384, y3, stat3);
    gemm_bn_kernel<256, 128><<<dim3(1876), 256, 0, stream>>>(y3, stat3, g3, b3, wb + 49152, y4, stat4);
    k5_kernel<<<dim3(3750), 256, 0, stream>>>(y2, y4, stat2, g2, b2, stat4, g4, b4,
                                              w_out, b_out, (float*)d_out);
}

// Round 6
// 157.647 us; speedup vs baseline: 1.0627x; 1.0627x over previous
//
#include <hip/hip_runtime.h>

#define NN   120000
#define NP   120064   // 1876 * 64, padded rows
#define EPSV 1e-5f
#define NSLICE 16

typedef __attribute__((ext_vector_type(8))) short          short8v;   // bf16 MFMA frag
typedef __attribute__((ext_vector_type(8))) unsigned short ushort8v;
typedef __attribute__((ext_vector_type(4))) float          f32x4;

typedef __attribute__((address_space(1))) const unsigned int gas_u32;
typedef __attribute__((address_space(3))) unsigned int       las_u32;

__device__ __forceinline__ float b2f(unsigned short u) {
    union { unsigned int i; float f; } x; x.i = ((unsigned int)u) << 16; return x.f;
}
__device__ __forceinline__ unsigned short f2b(float f) {
    union { float f; unsigned int i; } x; x.f = f;
    unsigned int i = x.i + 0x7FFFu + ((x.i >> 16) & 1u);
    return (unsigned short)(i >> 16);
}

// ---------------------------------------------------------------------------
// wprep: w2/w3/w4 (f32 [cout][kd]) -> bf16 MFMA-fragment-linear layout.
// Also zeroes the sliced-stats region (replaces hipMemsetAsync).
// ---------------------------------------------------------------------------
__global__ __launch_bounds__(256) void wprep_kernel(
    const float* __restrict__ w2, const float* __restrict__ w3,
    const float* __restrict__ w4, unsigned short* __restrict__ wb,
    float* __restrict__ statsAll)
{
    int t = blockIdx.x * 256 + threadIdx.x;
    if (t < 20480) statsAll[t] = 0.f;
    const float* src; int KD, ks; unsigned short* dst; int f;
    if (t < 16384)      { src = w2; KD = 128; ks = 2; dst = wb;         f = t; }
    else if (t < 49152) { src = w3; KD = 128; ks = 2; dst = wb + 16384; f = t - 16384; }
    else                { src = w4; KD = 256; ks = 3; dst = wb + 49152; f = t - 49152; }
    int e = f & 7, l = (f >> 3) & 63;
    int rest = f >> 9;
    int kb = rest & ((1 << ks) - 1);
    int cb = rest >> ks;
    int col = cb * 16 + (l & 15);
    int k = kb * 32 + (l >> 4) * 8 + e;
    dst[f] = f2b(src[col * KD + k]);
}

// ---------------------------------------------------------------------------
// K1: y1 = feat @ w1.T (K=5), raw bf16 output, sliced per-channel stats.
// ---------------------------------------------------------------------------
__global__ __launch_bounds__(256) void k1_kernel(
    const float* __restrict__ feat, const float* __restrict__ w1,
    unsigned short* __restrict__ y1, float* __restrict__ stat1)
{
    __shared__ float red[1024];
    const int tid = threadIdx.x;
    const int g = tid & 15;
    const int rsub = tid >> 4;
    const int rowbase = blockIdx.x * 128;

    float wr_[8][5];
#pragma unroll
    for (int j = 0; j < 8; ++j)
#pragma unroll
        for (int k = 0; k < 5; ++k)
            wr_[j][k] = w1[(g * 8 + j) * 5 + k];

    float ss[8] = {}, qq[8] = {};
#pragma unroll
    for (int p = 0; p < 8; ++p) {
        int row = rowbase + p * 16 + rsub;
        float f0 = 0.f, f1 = 0.f, f2 = 0.f, f3 = 0.f, f4 = 0.f;
        if (row < NN) {
            const float* fp = feat + (size_t)row * 5;
            f0 = fp[0]; f1 = fp[1]; f2 = fp[2]; f3 = fp[3]; f4 = fp[4];
        }
        ushort8v o;
#pragma unroll
        for (int j = 0; j < 8; ++j) {
            float y = f0*wr_[j][0] + f1*wr_[j][1] + f2*wr_[j][2] + f3*wr_[j][3] + f4*wr_[j][4];
            o[j] = f2b(y);
            ss[j] += y; qq[j] += y * y;
        }
        *(ushort8v*)(y1 + (size_t)row * 128 + g * 8) = o;
    }
#pragma unroll
    for (int j = 0; j < 8; ++j) {
        ss[j] += __shfl_xor(ss[j], 16); ss[j] += __shfl_xor(ss[j], 32);
        qq[j] += __shfl_xor(qq[j], 16); qq[j] += __shfl_xor(qq[j], 32);
    }
    const int w = tid >> 6, l = tid & 63;
    if ((l >> 4) == 0) {
#pragma unroll
        for (int j = 0; j < 8; ++j) {
            red[w * 128 + g * 8 + j]       = ss[j];
            red[512 + w * 128 + g * 8 + j] = qq[j];
        }
    }
    __syncthreads();
    if (tid < 128) {
        float s = red[tid] + red[128 + tid] + red[256 + tid] + red[384 + tid];
        float q = red[512 + tid] + red[640 + tid] + red[768 + tid] + red[896 + tid];
        float* dst = stat1 + (blockIdx.x & (NSLICE - 1)) * 256;
        atomicAdd(dst + tid,       s);
        atomicAdd(dst + 128 + tid, q);
    }
}

// ---------------------------------------------------------------------------
// GEMM v4: 64 rows x COUT per block, grid 1876.
// Wave partition: each wave owns ALL 64 rows x (COUT/4) cols -> no duplicated
// B loads; B frags pipelined in registers (cur/next, issued one kk ahead).
// A staged HBM->LDS via global_load_lds with pre-swizzled source; BN+relu
// applied at fragment-load time.
// ---------------------------------------------------------------------------
template<int KD, int COUT>
__global__ __launch_bounds__(256, (COUT == 256 || KD == 256) ? 3 : 4)
void gemm_bn_kernel(
    const unsigned short* __restrict__ X, const float* __restrict__ statsIn,
    const float* __restrict__ gIn, const float* __restrict__ bIn,
    const unsigned short* __restrict__ Wf, unsigned short* __restrict__ Y,
    float* __restrict__ statsOut)
{
    constexpr int KDB    = KD * 2;              // bytes per LDS A row
    constexpr int NKK    = KD / 32;             // MFMA k-steps
    constexpr int NNI    = COUT / 64;           // 16-col groups per wave
    constexpr int KBLK   = KD / 32;
    constexpr int ROUNDS = (64 * KDB) / 4096;   // 4 (KD=128) or 8 (KD=256)
    constexpr int PITCH  = COUT * 2 + 16;       // writeback scratch pitch
    constexpr int WBR    = (KD == 256) ? 64 : 32;   // writeback rows per pass
    constexpr int NPASS  = 64 / WBR;
    constexpr int TPR    = 256 / WBR;           // threads per row in store
    constexpr int UPT    = (COUT / 8) / TPR;    // 16B units per thread
    constexpr int ABYTES = ((64 * KDB) > (WBR * PITCH)) ? (64 * KDB) : (WBR * PITCH);

    __shared__ char  As[ABYTES];
    __shared__ float scl[KD], bia[KD];
    __shared__ float red[2 * COUT];

    const int tid = threadIdx.x;
    const int l = tid & 63, wv = tid >> 6;
    const int lm = l & 15, lg = l >> 4;
    const int rowbase = blockIdx.x * 64;
    const int cb0 = wv * NNI;                   // wave's first 16-col block

    // ---- stage A tile (64 x KD bf16) into swizzled LDS via DMA ----
#pragma unroll
    for (int rnd = 0; rnd < ROUNDS; ++rnd) {
        int s = rnd * 4096 + wv * 1024 + l * 16;
        int row = s / KDB;
        int colb = s % KDB;
        int srcb = colb ^ ((row & 7) << 4);
        const unsigned short* g = X + (size_t)(rowbase + row) * KD + (srcb >> 1);
        __builtin_amdgcn_global_load_lds((gas_u32*)g,
            (las_u32*)(As + rnd * 4096 + wv * 1024), 16, 0, 0);
    }

    // ---- B frags for kk=0 (registers) ----
    short8v bc[NNI], bn[NNI];
#pragma unroll
    for (int ni = 0; ni < NNI; ++ni)
        bc[ni] = *(const short8v*)(Wf + ((size_t)((cb0 + ni) * KBLK + 0) * 64 + l) * 8);

    // ---- BN params from sliced stats (overlaps DMA latency) ----
    if (tid < KD) {
        float s = 0.f, q = 0.f;
#pragma unroll 8
        for (int j = 0; j < NSLICE; ++j) {
            s += statsIn[j * 2 * KD + tid];
            q += statsIn[j * 2 * KD + KD + tid];
        }
        float mean = s * (1.0f / NN);
        float var  = q * (1.0f / NN) - mean * mean;
        float sc   = gIn[tid] * rsqrtf(var + EPSV);
        scl[tid] = sc;
        bia[tid] = bIn[tid] - mean * sc;
    }

    asm volatile("s_waitcnt vmcnt(0)" ::: "memory");
    __syncthreads();

    // ---- MFMA: A from LDS (+BN+relu in regs), B resident/pipelined ----
    f32x4 acc[4][NNI] = {};
#pragma unroll
    for (int kk = 0; kk < NKK; ++kk) {
        if (kk + 1 < NKK) {
#pragma unroll
            for (int ni = 0; ni < NNI; ++ni)
                bn[ni] = *(const short8v*)(Wf + ((size_t)((cb0 + ni) * KBLK + kk + 1) * 64 + l) * 8);
        }
        int k0 = kk * 32 + lg * 8;
        f32x4 s0 = *(const f32x4*)(scl + k0);
        f32x4 s1 = *(const f32x4*)(scl + k0 + 4);
        f32x4 c0 = *(const f32x4*)(bia + k0);
        f32x4 c1 = *(const f32x4*)(bia + k0 + 4);
        short8v a[4];
#pragma unroll
        for (int mi = 0; mi < 4; ++mi) {
            int row = mi * 16 + lm;
            ushort8v raw = *(const ushort8v*)(As + row * KDB + ((kk * 64 + lg * 16) ^ ((row & 7) << 4)));
            ushort8v o;
#pragma unroll
            for (int j = 0; j < 4; ++j)
                o[j] = f2b(fmaxf(b2f(raw[j]) * s0[j] + c0[j], 0.f));
#pragma unroll
            for (int j = 0; j < 4; ++j)
                o[4 + j] = f2b(fmaxf(b2f(raw[4 + j]) * s1[j] + c1[j], 0.f));
            a[mi] = (short8v)o;
        }
#pragma unroll
        for (int ni = 0; ni < NNI; ++ni)
#pragma unroll
            for (int mi = 0; mi < 4; ++mi)
                acc[mi][ni] = __builtin_amdgcn_mfma_f32_16x16x32_bf16(a[mi], bc[ni], acc[mi][ni], 0, 0, 0);
#pragma unroll
        for (int ni = 0; ni < NNI; ++ni)
            bc[ni] = bn[ni];
    }

    // ---- per-channel stats: disjoint channels per wave, no cross-wave add ----
#pragma unroll
    for (int ni = 0; ni < NNI; ++ni) {
        float s = 0.f, q = 0.f;
#pragma unroll
        for (int mi = 0; mi < 4; ++mi)
#pragma unroll
            for (int r = 0; r < 4; ++r) {
                int rowg = rowbase + mi * 16 + lg * 4 + r;
                float v = (rowg < NN) ? acc[mi][ni][r] : 0.f;
                s += v; q += v * v;
            }
        s += __shfl_xor(s, 16); s += __shfl_xor(s, 32);
        q += __shfl_xor(q, 16); q += __shfl_xor(q, 32);
        if (lg == 0) {
            int ch = (cb0 + ni) * 16 + lm;
            red[ch] = s; red[COUT + ch] = q;
        }
    }
    __syncthreads();
    {
        int slice = blockIdx.x & (NSLICE - 1);
        for (int ch = tid; ch < COUT; ch += 256) {
            atomicAdd(statsOut + (size_t)slice * 2 * COUT + ch,        red[ch]);
            atomicAdd(statsOut + (size_t)slice * 2 * COUT + COUT + ch, red[COUT + ch]);
        }
    }

    // ---- writeback via As scratch, NPASS passes of WBR rows ----
#pragma unroll
    for (int p = 0; p < NPASS; ++p) {
#pragma unroll
        for (int mi = 0; mi < 4; ++mi) {
            if (mi * 16 >= p * WBR && mi * 16 < (p + 1) * WBR) {
#pragma unroll
                for (int ni = 0; ni < NNI; ++ni)
#pragma unroll
                    for (int r = 0; r < 4; ++r) {
                        int rloc = mi * 16 - p * WBR + lg * 4 + r;
                        int col = (cb0 + ni) * 16 + lm;
                        *(unsigned short*)(As + rloc * PITCH + col * 2) = f2b(acc[mi][ni][r]);
                    }
            }
        }
        __syncthreads();
        {
            int rloc = tid / TPR;
            int u0 = (tid % TPR) * UPT;
            unsigned short* Yrow = Y + (size_t)(rowbase + p * WBR + rloc) * COUT + u0 * 8;
#pragma unroll
            for (int u = 0; u < UPT; ++u)
                *(ushort8v*)(Yrow + u * 8) =
                    *(const ushort8v*)(As + rloc * PITCH + (u0 + u) * 16);
        }
        if (p + 1 < NPASS) __syncthreads();
    }
}

// ---------------------------------------------------------------------------
// K5: x5 = relu( BN4(y4) + relu(BN2(y2)) ); logits = x5 @ w_out.T + b_out
// ---------------------------------------------------------------------------
__global__ __launch_bounds__(256) void k5_kernel(
    const unsigned short* __restrict__ y2, const unsigned short* __restrict__ y4,
    const float* __restrict__ stat2, const float* __restrict__ g2, const float* __restrict__ b2,
    const float* __restrict__ stat4, const float* __restrict__ g4, const float* __restrict__ b4,
    const float* __restrict__ w_out, const float* __restrict__ b_out,
    float* __restrict__ out)
{
    __shared__ float wT[128 * 8];
    __shared__ float sc2[128], bi2[128], sc4[128], bi4[128], bo[8];
    const int tid = threadIdx.x;

    if (tid < 128) {
        float s2 = 0.f, q2 = 0.f, s4 = 0.f, q4 = 0.f;
#pragma unroll 8
        for (int j = 0; j < NSLICE; ++j) {
            s2 += stat2[j * 256 + tid];       q2 += stat2[j * 256 + 128 + tid];
            s4 += stat4[j * 256 + tid];       q4 += stat4[j * 256 + 128 + tid];
        }
        float m2 = s2 * (1.0f / NN);
        float v2 = q2 * (1.0f / NN) - m2 * m2;
        float t2 = g2[tid] * rsqrtf(v2 + EPSV);
        sc2[tid] = t2; bi2[tid] = b2[tid] - m2 * t2;
        float m4 = s4 * (1.0f / NN);
        float v4 = q4 * (1.0f / NN) - m4 * m4;
        float t4 = g4[tid] * rsqrtf(v4 + EPSV);
        sc4[tid] = t4; bi4[tid] = b4[tid] - m4 * t4;
    }
    for (int i = tid; i < 1024; i += 256) wT[i] = w_out[(i & 7) * 128 + (i >> 3)];
    if (tid < 8) bo[tid] = b_out[tid];
    __syncthreads();

    const int l = tid & 63, wv = tid >> 6;
    const int sub = l & 7, rl = l >> 3;
    const int row = blockIdx.x * 32 + wv * 8 + rl;   // 3750*32 = 120000

    const ushort8v* p2 = (const ushort8v*)(y2 + (size_t)row * 128 + sub * 16);
    const ushort8v* p4 = (const ushort8v*)(y4 + (size_t)row * 128 + sub * 16);

    float p[8];
#pragma unroll
    for (int o = 0; o < 8; ++o) p[o] = 0.f;

#pragma unroll
    for (int jj = 0; jj < 2; ++jj) {
        ushort8v a2 = p2[jj];
        ushort8v a4 = p4[jj];
#pragma unroll
        for (int e = 0; e < 8; ++e) {
            int c = sub * 16 + jj * 8 + e;
            float i2 = fmaxf(b2f(a2[e]) * sc2[c] + bi2[c], 0.f);
            float x4 = b2f(a4[e]) * sc4[c] + bi4[c];
            float x5 = fmaxf(x4 + i2, 0.f);
            const f32x4* wp = (const f32x4*)(wT + c * 8);
            f32x4 wa = wp[0], wb = wp[1];
            p[0] += x5 * wa[0]; p[1] += x5 * wa[1]; p[2] += x5 * wa[2]; p[3] += x5 * wa[3];
            p[4] += x5 * wb[0]; p[5] += x5 * wb[1]; p[6] += x5 * wb[2]; p[7] += x5 * wb[3];
        }
    }
#pragma unroll
    for (int o = 0; o < 8; ++o) {
        p[o] += __shfl_xor(p[o], 1);
        p[o] += __shfl_xor(p[o], 2);
        p[o] += __shfl_xor(p[o], 4);
    }
    out[(size_t)row * 8 + sub] = p[sub] + bo[sub];
}

// ---------------------------------------------------------------------------
extern "C" void kernel_launch(void* const* d_in, const int* in_sizes, int n_in,
                              void* d_out, int out_size, void* d_ws, size_t ws_size,
                              hipStream_t stream)
{
    const float* feat  = (const float*)d_in[0];
    // d_in[1] coord, d_in[2] knn_idx, d_in[3] offset: dead code in reference
    const float* w1    = (const float*)d_in[4];
    const float* g1    = (const float*)d_in[5];
    const float* b1    = (const float*)d_in[6];
    const float* w2    = (const float*)d_in[7];
    const float* g2    = (const float*)d_in[8];
    const float* b2    = (const float*)d_in[9];
    const float* w3    = (const float*)d_in[10];
    const float* g3    = (const float*)d_in[11];
    const float* b3    = (const float*)d_in[12];
    const float* w4    = (const float*)d_in[13];
    const float* g4    = (const float*)d_in[14];
    const float* b4    = (const float*)d_in[15];
    const float* w_out = (const float*)d_in[16];
    const float* b_out = (const float*)d_in[17];

    char* ws = (char*)d_ws;
    const size_t sz128 = (size_t)NP * 128 * 2;   // bf16 N x 128
    const size_t sz256 = (size_t)NP * 256 * 2;   // bf16 N x 256
    unsigned short* y1 = (unsigned short*)(ws);
    unsigned short* y2 = (unsigned short*)(ws + sz128);
    unsigned short* y3 = (unsigned short*)(ws + 2 * sz128);
    unsigned short* y4 = (unsigned short*)(ws + 2 * sz128 + sz256);
    float* stats       = (float*)(ws + 3 * sz128 + sz256);
    // sliced stats: [16][2][C]
    float* stat1 = stats;            // 16*2*128 = 4096
    float* stat2 = stats + 4096;     // 4096
    float* stat3 = stats + 8192;     // 16*2*256 = 8192
    float* stat4 = stats + 16384;    // 4096
    unsigned short* wb = (unsigned short*)(stats + 20480);  // 81920 bf16 frag weights

    wprep_kernel<<<dim3(320), 256, 0, stream>>>(w2, w3, w4, wb, stats);
    k1_kernel<<<dim3(938), 256, 0, stream>>>(feat, w1, y1, stat1);
    gemm_bn_kernel<128, 128><<<dim3(1876), 256, 0, stream>>>(y1, stat1, g1, b1, wb,         y2, stat2);
    gemm_bn_kernel<128, 256><<<dim3(1876), 256, 0, stream>>>(y2, stat2, g2, b2, wb + 16384, y3, stat3);
    gemm_bn_kernel<256, 128><<<dim3(1876), 256, 0, stream>>>(y3, stat3, g3, b3, wb + 49152, y4, stat4);
    k5_kernel<<<dim3(3750), 256, 0, stream>>>(y2, y4, stat2, g2, b2, stat4, g4, b4,
                                              w_out, b_out, (float*)d_out);
}

// Round 7
// 136.451 us; speedup vs baseline: 1.2278x; 1.1553x over previous
//
#include <hip/hip_runtime.h>
#include <hip/hip_bf16.h>

#define NN   120000
#define NP   120064   // 1876 * 64, padded rows
#define EPSV 1e-5f
#define NSLICE 16

typedef __attribute__((ext_vector_type(8))) short          short8v;   // bf16 MFMA frag
typedef __attribute__((ext_vector_type(8))) unsigned short ushort8v;
typedef __attribute__((ext_vector_type(4))) float          f32x4;

__device__ __forceinline__ float b2f(unsigned short u) {
    union { unsigned int i; float f; } x; x.i = ((unsigned int)u) << 16; return x.f;
}
__device__ __forceinline__ unsigned short f2b(float f) {
    __hip_bfloat16 h = __float2bfloat16(f);   // RTNE; compiler packs pairs into v_cvt_pk_bf16_f32
    return *reinterpret_cast<unsigned short*>(&h);
}

// ---------------------------------------------------------------------------
// prep: blocks [0,320): w2/w3/w4 -> bf16 MFMA-fragment-linear layout.
//       blocks [320,1258): stats of y1 = feat @ w1.T (no y1 store).
// stats region is zeroed by hipMemsetAsync before this launch.
// ---------------------------------------------------------------------------
__global__ __launch_bounds__(256) void prep_kernel(
    const float* __restrict__ w2, const float* __restrict__ w3,
    const float* __restrict__ w4, unsigned short* __restrict__ wb,
    const float* __restrict__ feat, const float* __restrict__ w1,
    float* __restrict__ stat1)
{
    const int bid = blockIdx.x;
    const int tid = threadIdx.x;
    if (bid < 320) {
        int t = bid * 256 + tid;
        const float* src; int KD, ks; unsigned short* dst; int f;
        if (t < 16384)      { src = w2; KD = 128; ks = 2; dst = wb;         f = t; }
        else if (t < 49152) { src = w3; KD = 128; ks = 2; dst = wb + 16384; f = t - 16384; }
        else                { src = w4; KD = 256; ks = 3; dst = wb + 49152; f = t - 49152; }
        int e = f & 7, l = (f >> 3) & 63;
        int rest = f >> 9;
        int kb = rest & ((1 << ks) - 1);
        int cb = rest >> ks;
        int col = cb * 16 + (l & 15);
        int k = kb * 32 + (l >> 4) * 8 + e;
        dst[f] = f2b(src[col * KD + k]);
        return;
    }
    // ---- stats of y1 (no store) ----
    __shared__ float red[1024];
    const int g = tid & 15;
    const int rsub = tid >> 4;
    const int rowbase = (bid - 320) * 128;

    float wr_[8][5];
#pragma unroll
    for (int j = 0; j < 8; ++j)
#pragma unroll
        for (int k = 0; k < 5; ++k)
            wr_[j][k] = w1[(g * 8 + j) * 5 + k];

    float ss[8] = {}, qq[8] = {};
#pragma unroll
    for (int p = 0; p < 8; ++p) {
        int row = rowbase + p * 16 + rsub;
        if (row < NN) {
            const float* fp = feat + (size_t)row * 5;
            float f0 = fp[0], f1 = fp[1], f2 = fp[2], f3 = fp[3], f4 = fp[4];
#pragma unroll
            for (int j = 0; j < 8; ++j) {
                float y = f0*wr_[j][0] + f1*wr_[j][1] + f2*wr_[j][2] + f3*wr_[j][3] + f4*wr_[j][4];
                ss[j] += y; qq[j] += y * y;
            }
        }
    }
#pragma unroll
    for (int j = 0; j < 8; ++j) {
        ss[j] += __shfl_xor(ss[j], 16); ss[j] += __shfl_xor(ss[j], 32);
        qq[j] += __shfl_xor(qq[j], 16); qq[j] += __shfl_xor(qq[j], 32);
    }
    const int w = tid >> 6, l = tid & 63;
    if ((l >> 4) == 0) {
#pragma unroll
        for (int j = 0; j < 8; ++j) {
            red[w * 128 + g * 8 + j]       = ss[j];
            red[512 + w * 128 + g * 8 + j] = qq[j];
        }
    }
    __syncthreads();
    if (tid < 128) {
        float s = red[tid] + red[128 + tid] + red[256 + tid] + red[384 + tid];
        float q = red[512 + tid] + red[640 + tid] + red[768 + tid] + red[896 + tid];
        float* dst = stat1 + ((bid - 320) & (NSLICE - 1)) * 256;
        atomicAdd(dst + tid,       s);
        atomicAdd(dst + 128 + tid, q);
    }
}

// ---------------------------------------------------------------------------
// gemm1: x1 = BN1relu(feat @ w1.T) computed in-block (VALU, K=5),
//        y2 = x1 @ w2.T (MFMA), write y2 + stat2. 64 rows/block.
// ---------------------------------------------------------------------------
__global__ __launch_bounds__(256, 4) void gemm1_kernel(
    const float* __restrict__ feat, const float* __restrict__ w1,
    const float* __restrict__ stat1, const float* __restrict__ g1, const float* __restrict__ b1,
    const unsigned short* __restrict__ Wf, unsigned short* __restrict__ Y,
    float* __restrict__ statsOut)
{
    __shared__ float featL[64 * 5];
    __shared__ float w1L[128 * 5];
    __shared__ float scl[128], bia[128];
    __shared__ char  xs[16384];          // x1 tile (64x128 bf16, swizzled); reused for writeback
    __shared__ float red[256];

    const int tid = threadIdx.x;
    const int l = tid & 63, wv = tid >> 6;
    const int lm = l & 15, lg = l >> 4;
    const int rowbase = blockIdx.x * 64;

    if (tid < 64) {
        int row = rowbase + tid;
        if (row < NN) {
            const float* fp = feat + (size_t)row * 5;
#pragma unroll
            for (int k = 0; k < 5; ++k) featL[tid * 5 + k] = fp[k];
        } else {
#pragma unroll
            for (int k = 0; k < 5; ++k) featL[tid * 5 + k] = 0.f;
        }
    }
    if (tid < 160) *(f32x4*)(w1L + tid * 4) = *(const f32x4*)(w1 + tid * 4);
    if (tid < 128) {
        float s = 0.f, q = 0.f;
#pragma unroll 8
        for (int j = 0; j < NSLICE; ++j) {
            s += stat1[j * 256 + tid];
            q += stat1[j * 256 + 128 + tid];
        }
        float mean = s * (1.0f / NN);
        float var  = q * (1.0f / NN) - mean * mean;
        float sc   = g1[tid] * rsqrtf(var + EPSV);
        scl[tid] = sc;
        bia[tid] = b1[tid] - mean * sc;
    }
    __syncthreads();

    // ---- x1 tile: thread owns 1 row x 32 cols ----
    {
        int rloc = tid >> 2, c0 = (tid & 3) * 32;
        float f0 = featL[rloc*5], f1 = featL[rloc*5+1], f2 = featL[rloc*5+2],
              f3 = featL[rloc*5+3], f4 = featL[rloc*5+4];
#pragma unroll
        for (int u = 0; u < 4; ++u) {
            ushort8v o;
#pragma unroll
            for (int e = 0; e < 8; ++e) {
                int c = c0 + u * 8 + e;
                const float* wp = w1L + c * 5;
                float y = f0*wp[0] + f1*wp[1] + f2*wp[2] + f3*wp[3] + f4*wp[4];
                o[e] = f2b(fmaxf(y * scl[c] + bia[c], 0.f));
            }
            *(ushort8v*)(xs + rloc * 256 + (((c0 + u * 8) * 2) ^ ((rloc & 7) << 4))) = o;
        }
    }
    __syncthreads();

    // ---- MFMA: KD=128, COUT=128, wave owns 32 cols (NNI=2) ----
    const int cb0 = wv * 2;
    f32x4 acc[4][2] = {};
#pragma unroll
    for (int kk = 0; kk < 4; ++kk) {
        short8v bl[2];
#pragma unroll
        for (int ni = 0; ni < 2; ++ni)
            bl[ni] = *(const short8v*)(Wf + ((size_t)((cb0 + ni) * 4 + kk) * 64 + l) * 8);
        short8v a[4];
#pragma unroll
        for (int mi = 0; mi < 4; ++mi) {
            int row = mi * 16 + lm;
            a[mi] = *(const short8v*)(xs + row * 256 + ((kk * 64 + lg * 16) ^ ((row & 7) << 4)));
        }
#pragma unroll
        for (int ni = 0; ni < 2; ++ni)
#pragma unroll
            for (int mi = 0; mi < 4; ++mi)
                acc[mi][ni] = __builtin_amdgcn_mfma_f32_16x16x32_bf16(a[mi], bl[ni], acc[mi][ni], 0, 0, 0);
    }

    // ---- stat2 ----
#pragma unroll
    for (int ni = 0; ni < 2; ++ni) {
        float s = 0.f, q = 0.f;
#pragma unroll
        for (int mi = 0; mi < 4; ++mi)
#pragma unroll
            for (int r = 0; r < 4; ++r) {
                int rowg = rowbase + mi * 16 + lg * 4 + r;
                float v = (rowg < NN) ? acc[mi][ni][r] : 0.f;
                s += v; q += v * v;
            }
        s += __shfl_xor(s, 16); s += __shfl_xor(s, 32);
        q += __shfl_xor(q, 16); q += __shfl_xor(q, 32);
        if (lg == 0) {
            int ch = (cb0 + ni) * 16 + lm;
            red[ch] = s; red[128 + ch] = q;
        }
    }
    __syncthreads();
    if (tid < 128) {
        int slice = blockIdx.x & (NSLICE - 1);
        atomicAdd(statsOut + (size_t)slice * 256 + tid,       red[tid]);
        atomicAdd(statsOut + (size_t)slice * 256 + 128 + tid, red[128 + tid]);
    }

    // ---- writeback y2 via xs scratch (PITCH=272), two 32-row passes ----
#pragma unroll
    for (int p = 0; p < 2; ++p) {
#pragma unroll
        for (int mi = 0; mi < 4; ++mi) {
            if (mi * 16 >= p * 32 && mi * 16 < (p + 1) * 32) {
#pragma unroll
                for (int ni = 0; ni < 2; ++ni)
#pragma unroll
                    for (int r = 0; r < 4; ++r) {
                        int rloc = mi * 16 - p * 32 + lg * 4 + r;
                        int col = (cb0 + ni) * 16 + lm;
                        *(unsigned short*)(xs + rloc * 272 + col * 2) = f2b(acc[mi][ni][r]);
                    }
            }
        }
        __syncthreads();
        {
            int rloc = tid >> 3;
            int u0 = (tid & 7) * 2;
            unsigned short* Yrow = Y + (size_t)(rowbase + p * 32 + rloc) * 128 + u0 * 8;
#pragma unroll
            for (int u = 0; u < 2; ++u)
                *(ushort8v*)(Yrow + u * 8) =
                    *(const ushort8v*)(xs + rloc * 272 + (u0 + u) * 16);
        }
        if (p == 0) __syncthreads();
    }
}

// ---------------------------------------------------------------------------
// gemm2s: stats-only. x2 = BN2relu(y2); y3 = x2 @ w3.T; accumulate stat3;
// y3 is NOT stored (recomputed in gemm34).
// ---------------------------------------------------------------------------
__global__ __launch_bounds__(256, 4) void gemm2s_kernel(
    const unsigned short* __restrict__ X, const float* __restrict__ statsIn,
    const float* __restrict__ gIn, const float* __restrict__ bIn,
    const unsigned short* __restrict__ Wf, float* __restrict__ statsOut)
{
    __shared__ char  xs[16384];
    __shared__ float scl[128], bia[128];
    __shared__ float red[512];

    const int tid = threadIdx.x;
    const int l = tid & 63, wv = tid >> 6;
    const int lm = l & 15, lg = l >> 4;
    const int rowbase = blockIdx.x * 64;
    const int cb0 = wv * 4;

    // issue tile loads to regs (coalesced), overlap with param compute
    ushort8v xr[4];
#pragma unroll
    for (int i = 0; i < 4; ++i) {
        int u = i * 256 + tid;
        xr[i] = *(const ushort8v*)(X + (size_t)(rowbase + (u >> 4)) * 128 + (u & 15) * 8);
    }
    if (tid < 128) {
        float s = 0.f, q = 0.f;
#pragma unroll 8
        for (int j = 0; j < NSLICE; ++j) {
            s += statsIn[j * 256 + tid];
            q += statsIn[j * 256 + 128 + tid];
        }
        float mean = s * (1.0f / NN);
        float var  = q * (1.0f / NN) - mean * mean;
        float sc   = gIn[tid] * rsqrtf(var + EPSV);
        scl[tid] = sc;
        bia[tid] = bIn[tid] - mean * sc;
    }
    __syncthreads();
#pragma unroll
    for (int i = 0; i < 4; ++i) {
        int u = i * 256 + tid;
        int row = u >> 4, cu = u & 15;
        f32x4 s0 = *(const f32x4*)(scl + cu * 8);
        f32x4 s1 = *(const f32x4*)(scl + cu * 8 + 4);
        f32x4 c0 = *(const f32x4*)(bia + cu * 8);
        f32x4 c1 = *(const f32x4*)(bia + cu * 8 + 4);
        ushort8v v = xr[i], o;
#pragma unroll
        for (int j = 0; j < 4; ++j) o[j]     = f2b(fmaxf(b2f(v[j])     * s0[j] + c0[j], 0.f));
#pragma unroll
        for (int j = 0; j < 4; ++j) o[4 + j] = f2b(fmaxf(b2f(v[4 + j]) * s1[j] + c1[j], 0.f));
        *(ushort8v*)(xs + row * 256 + ((cu * 16) ^ ((row & 7) << 4))) = o;
    }
    __syncthreads();

    // MFMA: KD=128, COUT=256, wave owns 64 cols (NNI=4)
    f32x4 acc[4][4] = {};
#pragma unroll
    for (int kk = 0; kk < 4; ++kk) {
        short8v bl[4];
#pragma unroll
        for (int ni = 0; ni < 4; ++ni)
            bl[ni] = *(const short8v*)(Wf + ((size_t)((cb0 + ni) * 4 + kk) * 64 + l) * 8);
        short8v a[4];
#pragma unroll
        for (int mi = 0; mi < 4; ++mi) {
            int row = mi * 16 + lm;
            a[mi] = *(const short8v*)(xs + row * 256 + ((kk * 64 + lg * 16) ^ ((row & 7) << 4)));
        }
#pragma unroll
        for (int ni = 0; ni < 4; ++ni)
#pragma unroll
            for (int mi = 0; mi < 4; ++mi)
                acc[mi][ni] = __builtin_amdgcn_mfma_f32_16x16x32_bf16(a[mi], bl[ni], acc[mi][ni], 0, 0, 0);
    }

    // stat3 (COUT=256)
#pragma unroll
    for (int ni = 0; ni < 4; ++ni) {
        float s = 0.f, q = 0.f;
#pragma unroll
        for (int mi = 0; mi < 4; ++mi)
#pragma unroll
            for (int r = 0; r < 4; ++r) {
                int rowg = rowbase + mi * 16 + lg * 4 + r;
                float v = (rowg < NN) ? acc[mi][ni][r] : 0.f;
                s += v; q += v * v;
            }
        s += __shfl_xor(s, 16); s += __shfl_xor(s, 32);
        q += __shfl_xor(q, 16); q += __shfl_xor(q, 32);
        if (lg == 0) {
            int ch = (cb0 + ni) * 16 + lm;
            red[ch] = s; red[256 + ch] = q;
        }
    }
    __syncthreads();
    {
        int slice = blockIdx.x & (NSLICE - 1);
        atomicAdd(statsOut + (size_t)slice * 512 + tid,       red[tid]);
        atomicAdd(statsOut + (size_t)slice * 512 + 256 + tid, red[256 + tid]);
    }
}

// ---------------------------------------------------------------------------
// gemm34: x2 = BN2relu(y2); y3 = x2 @ w3.T; x3 = BN3relu(y3) staged via LDS
// (pitch 520B, conflict-free); y4 = x3 @ w4.T; write y4 + stat4.
// ---------------------------------------------------------------------------
__global__ __launch_bounds__(256, 3) void gemm34_kernel(
    const unsigned short* __restrict__ X,
    const float* __restrict__ stat2, const float* __restrict__ g2v, const float* __restrict__ b2v,
    const float* __restrict__ stat3, const float* __restrict__ g3v, const float* __restrict__ b3v,
    const unsigned short* __restrict__ Wf3, const unsigned short* __restrict__ Wf4,
    unsigned short* __restrict__ Y, float* __restrict__ statsOut)
{
    __shared__ char  xs[16384];          // x2 tile; reused for y4 writeback
    __shared__ char  x3s[64 * 520];      // x3 tile (64x256 bf16, pitch 520B)
    __shared__ float scl2[128], bia2[128], scl3[256], bia3[256];
    __shared__ float red[256];

    const int tid = threadIdx.x;
    const int l = tid & 63, wv = tid >> 6;
    const int lm = l & 15, lg = l >> 4;
    const int rowbase = blockIdx.x * 64;

    ushort8v xr[4];
#pragma unroll
    for (int i = 0; i < 4; ++i) {
        int u = i * 256 + tid;
        xr[i] = *(const ushort8v*)(X + (size_t)(rowbase + (u >> 4)) * 128 + (u & 15) * 8);
    }
    if (tid < 128) {
        float s = 0.f, q = 0.f;
#pragma unroll 8
        for (int j = 0; j < NSLICE; ++j) {
            s += stat2[j * 256 + tid];
            q += stat2[j * 256 + 128 + tid];
        }
        float mean = s * (1.0f / NN);
        float var  = q * (1.0f / NN) - mean * mean;
        float sc   = g2v[tid] * rsqrtf(var + EPSV);
        scl2[tid] = sc;
        bia2[tid] = b2v[tid] - mean * sc;
    }
    {
        float s = 0.f, q = 0.f;
#pragma unroll 8
        for (int j = 0; j < NSLICE; ++j) {
            s += stat3[j * 512 + tid];
            q += stat3[j * 512 + 256 + tid];
        }
        float mean = s * (1.0f / NN);
        float var  = q * (1.0f / NN) - mean * mean;
        float sc   = g3v[tid] * rsqrtf(var + EPSV);
        scl3[tid] = sc;
        bia3[tid] = b3v[tid] - mean * sc;
    }
    __syncthreads();
#pragma unroll
    for (int i = 0; i < 4; ++i) {
        int u = i * 256 + tid;
        int row = u >> 4, cu = u & 15;
        f32x4 s0 = *(const f32x4*)(scl2 + cu * 8);
        f32x4 s1 = *(const f32x4*)(scl2 + cu * 8 + 4);
        f32x4 c0 = *(const f32x4*)(bia2 + cu * 8);
        f32x4 c1 = *(const f32x4*)(bia2 + cu * 8 + 4);
        ushort8v v = xr[i], o;
#pragma unroll
        for (int j = 0; j < 4; ++j) o[j]     = f2b(fmaxf(b2f(v[j])     * s0[j] + c0[j], 0.f));
#pragma unroll
        for (int j = 0; j < 4; ++j) o[4 + j] = f2b(fmaxf(b2f(v[4 + j]) * s1[j] + c1[j], 0.f));
        *(ushort8v*)(xs + row * 256 + ((cu * 16) ^ ((row & 7) << 4))) = o;
    }
    __syncthreads();

    // ---- MFMA1: y3 (KD=128, COUT=256, NNI=4) ----
    const int cb0 = wv * 4;
    f32x4 acc3[4][4] = {};
#pragma unroll
    for (int kk = 0; kk < 4; ++kk) {
        short8v bl[4];
#pragma unroll
        for (int ni = 0; ni < 4; ++ni)
            bl[ni] = *(const short8v*)(Wf3 + ((size_t)((cb0 + ni) * 4 + kk) * 64 + l) * 8);
        short8v a[4];
#pragma unroll
        for (int mi = 0; mi < 4; ++mi) {
            int row = mi * 16 + lm;
            a[mi] = *(const short8v*)(xs + row * 256 + ((kk * 64 + lg * 16) ^ ((row & 7) << 4)));
        }
#pragma unroll
        for (int ni = 0; ni < 4; ++ni)
#pragma unroll
            for (int mi = 0; mi < 4; ++mi)
                acc3[mi][ni] = __builtin_amdgcn_mfma_f32_16x16x32_bf16(a[mi], bl[ni], acc3[mi][ni], 0, 0, 0);
    }

    // ---- x3 = BN3relu(y3) -> x3s (pitch 520B; conflict-free b16 writes) ----
#pragma unroll
    for (int ni = 0; ni < 4; ++ni) {
        int col = (cb0 + ni) * 16 + lm;
        float sc = scl3[col], bi = bia3[col];
#pragma unroll
        for (int mi = 0; mi < 4; ++mi)
#pragma unroll
            for (int r = 0; r < 4; ++r) {
                int row = mi * 16 + lg * 4 + r;
                *(unsigned short*)(x3s + row * 520 + col * 2) =
                    f2b(fmaxf(acc3[mi][ni][r] * sc + bi, 0.f));
            }
    }
    __syncthreads();

    // ---- MFMA2: y4 (K=256 -> NKK=8, COUT=128, NNI=2) ----
    const int cb02 = wv * 2;
    f32x4 acc4[4][2] = {};
#pragma unroll
    for (int kk = 0; kk < 8; ++kk) {
        short8v bl[2];
#pragma unroll
        for (int ni = 0; ni < 2; ++ni)
            bl[ni] = *(const short8v*)(Wf4 + ((size_t)((cb02 + ni) * 8 + kk) * 64 + l) * 8);
        short8v a[4];
#pragma unroll
        for (int mi = 0; mi < 4; ++mi) {
            int row = mi * 16 + lm;
            a[mi] = *(const short8v*)(x3s + row * 520 + (kk * 64 + lg * 16));
        }
#pragma unroll
        for (int ni = 0; ni < 2; ++ni)
#pragma unroll
            for (int mi = 0; mi < 4; ++mi)
                acc4[mi][ni] = __builtin_amdgcn_mfma_f32_16x16x32_bf16(a[mi], bl[ni], acc4[mi][ni], 0, 0, 0);
    }

    // ---- stat4 ----
#pragma unroll
    for (int ni = 0; ni < 2; ++ni) {
        float s = 0.f, q = 0.f;
#pragma unroll
        for (int mi = 0; mi < 4; ++mi)
#pragma unroll
            for (int r = 0; r < 4; ++r) {
                int rowg = rowbase + mi * 16 + lg * 4 + r;
                float v = (rowg < NN) ? acc4[mi][ni][r] : 0.f;
                s += v; q += v * v;
            }
        s += __shfl_xor(s, 16); s += __shfl_xor(s, 32);
        q += __shfl_xor(q, 16); q += __shfl_xor(q, 32);
        if (lg == 0) {
            int ch = (cb02 + ni) * 16 + lm;
            red[ch] = s; red[128 + ch] = q;
        }
    }
    __syncthreads();
    if (tid < 128) {
        int slice = blockIdx.x & (NSLICE - 1);
        atomicAdd(statsOut + (size_t)slice * 256 + tid,       red[tid]);
        atomicAdd(statsOut + (size_t)slice * 256 + 128 + tid, red[128 + tid]);
    }

    // ---- writeback y4 via xs scratch ----
#pragma unroll
    for (int p = 0; p < 2; ++p) {
#pragma unroll
        for (int mi = 0; mi < 4; ++mi) {
            if (mi * 16 >= p * 32 && mi * 16 < (p + 1) * 32) {
#pragma unroll
                for (int ni = 0; ni < 2; ++ni)
#pragma unroll
                    for (int r = 0; r < 4; ++r) {
                        int rloc = mi * 16 - p * 32 + lg * 4 + r;
                        int col = (cb02 + ni) * 16 + lm;
                        *(unsigned short*)(xs + rloc * 272 + col * 2) = f2b(acc4[mi][ni][r]);
                    }
            }
        }
        __syncthreads();
        {
            int rloc = tid >> 3;
            int u0 = (tid & 7) * 2;
            unsigned short* Yrow = Y + (size_t)(rowbase + p * 32 + rloc) * 128 + u0 * 8;
#pragma unroll
            for (int u = 0; u < 2; ++u)
                *(ushort8v*)(Yrow + u * 8) =
                    *(const ushort8v*)(xs + rloc * 272 + (u0 + u) * 16);
        }
        if (p == 0) __syncthreads();
    }
}

// ---------------------------------------------------------------------------
// K5: x5 = relu( BN4(y4) + relu(BN2(y2)) ); logits = x5 @ w_out.T + b_out
// ---------------------------------------------------------------------------
__global__ __launch_bounds__(256) void k5_kernel(
    const unsigned short* __restrict__ y2, const unsigned short* __restrict__ y4,
    const float* __restrict__ stat2, const float* __restrict__ g2, const float* __restrict__ b2,
    const float* __restrict__ stat4, const float* __restrict__ g4, const float* __restrict__ b4,
    const float* __restrict__ w_out, const float* __restrict__ b_out,
    float* __restrict__ out)
{
    __shared__ float wT[128 * 8];
    __shared__ float sc2[128], bi2[128], sc4[128], bi4[128], bo[8];
    const int tid = threadIdx.x;

    if (tid < 128) {
        float s2 = 0.f, q2 = 0.f, s4 = 0.f, q4 = 0.f;
#pragma unroll 8
        for (int j = 0; j < NSLICE; ++j) {
            s2 += stat2[j * 256 + tid];       q2 += stat2[j * 256 + 128 + tid];
            s4 += stat4[j * 256 + tid];       q4 += stat4[j * 256 + 128 + tid];
        }
        float m2 = s2 * (1.0f / NN);
        float v2 = q2 * (1.0f / NN) - m2 * m2;
        float t2 = g2[tid] * rsqrtf(v2 + EPSV);
        sc2[tid] = t2; bi2[tid] = b2[tid] - m2 * t2;
        float m4 = s4 * (1.0f / NN);
        float v4 = q4 * (1.0f / NN) - m4 * m4;
        float t4 = g4[tid] * rsqrtf(v4 + EPSV);
        sc4[tid] = t4; bi4[tid] = b4[tid] - m4 * t4;
    }
    for (int i = tid; i < 1024; i += 256) wT[i] = w_out[(i & 7) * 128 + (i >> 3)];
    if (tid < 8) bo[tid] = b_out[tid];
    __syncthreads();

    const int l = tid & 63, wv = tid >> 6;
    const int sub = l & 7, rl = l >> 3;
    const int row = blockIdx.x * 32 + wv * 8 + rl;   // 3750*32 = 120000

    const ushort8v* p2 = (const ushort8v*)(y2 + (size_t)row * 128 + sub * 16);
    const ushort8v* p4 = (const ushort8v*)(y4 + (size_t)row * 128 + sub * 16);

    float p[8];
#pragma unroll
    for (int o = 0; o < 8; ++o) p[o] = 0.f;

#pragma unroll
    for (int jj = 0; jj < 2; ++jj) {
        ushort8v a2 = p2[jj];
        ushort8v a4 = p4[jj];
#pragma unroll
        for (int e = 0; e < 8; ++e) {
            int c = sub * 16 + jj * 8 + e;
            float i2 = fmaxf(b2f(a2[e]) * sc2[c] + bi2[c], 0.f);
            float x4 = b2f(a4[e]) * sc4[c] + bi4[c];
            float x5 = fmaxf(x4 + i2, 0.f);
            const f32x4* wp = (const f32x4*)(wT + c * 8);
            f32x4 wa = wp[0], wb = wp[1];
            p[0] += x5 * wa[0]; p[1] += x5 * wa[1]; p[2] += x5 * wa[2]; p[3] += x5 * wa[3];
            p[4] += x5 * wb[0]; p[5] += x5 * wb[1]; p[6] += x5 * wb[2]; p[7] += x5 * wb[3];
        }
    }
#pragma unroll
    for (int o = 0; o < 8; ++o) {
        p[o] += __shfl_xor(p[o], 1);
        p[o] += __shfl_xor(p[o], 2);
        p[o] += __shfl_xor(p[o], 4);
    }
    out[(size_t)row * 8 + sub] = p[sub] + bo[sub];
}

// ---------------------------------------------------------------------------
extern "C" void kernel_launch(void* const* d_in, const int* in_sizes, int n_in,
                              void* d_out, int out_size, void* d_ws, size_t ws_size,
                              hipStream_t stream)
{
    const float* feat  = (const float*)d_in[0];
    // d_in[1] coord, d_in[2] knn_idx, d_in[3] offset: dead code in reference
    const float* w1    = (const float*)d_in[4];
    const float* g1    = (const float*)d_in[5];
    const float* b1    = (const float*)d_in[6];
    const float* w2    = (const float*)d_in[7];
    const float* g2    = (const float*)d_in[8];
    const float* b2    = (const float*)d_in[9];
    const float* w3    = (const float*)d_in[10];
    const float* g3    = (const float*)d_in[11];
    const float* b3    = (const float*)d_in[12];
    const float* w4    = (const float*)d_in[13];
    const float* g4    = (const float*)d_in[14];
    const float* b4    = (const float*)d_in[15];
    const float* w_out = (const float*)d_in[16];
    const float* b_out = (const float*)d_in[17];

    char* ws = (char*)d_ws;
    const size_t sz128 = (size_t)NP * 128 * 2;   // bf16 N x 128
    unsigned short* y2 = (unsigned short*)(ws);
    unsigned short* y4 = (unsigned short*)(ws + sz128);
    float* stats       = (float*)(ws + 2 * sz128);
    // sliced stats: stat1 [16][2][128], stat2 [16][2][128], stat3 [16][2][256], stat4 [16][2][128]
    float* stat1 = stats;            // 4096
    float* stat2 = stats + 4096;     // 4096
    float* stat3 = stats + 8192;     // 8192
    float* stat4 = stats + 16384;    // 4096
    unsigned short* wb = (unsigned short*)(stats + 20480);  // 81920 bf16 frag weights

    hipMemsetAsync(stats, 0, 20480 * sizeof(float), stream);

    prep_kernel<<<dim3(320 + 938), 256, 0, stream>>>(w2, w3, w4, wb, feat, w1, stat1);
    gemm1_kernel<<<dim3(1876), 256, 0, stream>>>(feat, w1, stat1, g1, b1, wb, y2, stat2);
    gemm2s_kernel<<<dim3(1876), 256, 0, stream>>>(y2, stat2, g2, b2, wb + 16384, stat3);
    gemm34_kernel<<<dim3(1876), 256, 0, stream>>>(y2, stat2, g2, b2, stat3, g3, b3,
                                                  wb + 16384, wb + 49152, y4, stat4);
    k5_kernel<<<dim3(3750), 256, 0, stream>>>(y2, y4, stat2, g2, b2, stat4, g4, b4,
                                              w_out, b_out, (float*)d_out);
}